// Round 10
// baseline (149.189 us; speedup 1.0000x reference)
//
#include <hip/hip_runtime.h>

#define BATCH 8192
#define IN 128
#define OUT 128
#define ROW (IN * 18)            // 2304 floats per cf output row
#define WS_NEED (294912u * 2u)   // 576 KB bf16 re-tiled cf

typedef short bf16x8 __attribute__((ext_vector_type(8)));
typedef float f32x16 __attribute__((ext_vector_type(16)));

static __device__ __forceinline__ unsigned short f2bf(float f) {
    union { float f; unsigned u; } v; v.f = f;
    unsigned r = v.u + 0x7fffu + ((v.u >> 16) & 1u);   // RNE
    return (unsigned short)(r >> 16);
}
static __device__ __forceinline__ bf16x8 as_bf16x8(uint4 v) {
    union { uint4 u; bf16x8 b; } x; x.u = v; return x.b;
}
static __device__ __forceinline__ float fast_tanh(float v) {
    float e = __expf(2.0f * v);
    return 1.0f - 2.0f * __builtin_amdgcn_rcpf(e + 1.0f);
}

// Re-tile cf into K' = [128 cells x 16 cols] ++ [256 spill] (k-octet major):
// main octet q = 2i + c8  -> cf[o][18i + 8*c8 + e]      (cols 0..15 of cell i)
// spill octet q = 256+qs  -> cf[o][18*((8qs+e)>>1) + 16 + ((8qs+e)&1)]  (cols 16,17)
__global__ __launch_bounds__(256) void cvt_kernel(const float* __restrict__ cf,
                                                  unsigned short* __restrict__ cfb3) {
    int tid = blockIdx.x * 256 + threadIdx.x;   // 0 .. 36863
    int o = tid & 127;
    int q = tid >> 7;                           // 0..287
    unsigned short v[8];
    if (q < 256) {
        const float* p = cf + o * ROW + (q >> 1) * 18 + (q & 1) * 8;
        #pragma unroll
        for (int e = 0; e < 8; ++e) v[e] = f2bf(p[e]);
    } else {
        int qs = q - 256;
        #pragma unroll
        for (int e = 0; e < 8; ++e) {
            int kl = qs * 8 + e;
            v[e] = f2bf(cf[o * ROW + (kl >> 1) * 18 + 16 + (kl & 1)]);
        }
    }
    uint4 pk;
    pk.x = (unsigned)v[0] | ((unsigned)v[1] << 16);
    pk.y = (unsigned)v[2] | ((unsigned)v[3] << 16);
    pk.z = (unsigned)v[4] | ((unsigned)v[5] << 16);
    pk.w = (unsigned)v[6] | ((unsigned)v[7] << 16);
    ((uint4*)cfb3)[q * 128 + o] = pk;
}

// 256 blocks x 1024 thr (16 waves, 4/SIMD). Block = 32 batch rows x 128 o.
// Wave w: K-slice = cells [8w, 8w+8) + spill step w. A built in registers.
// CRITICAL: K-loop is unroll-1 — full unroll hoists 36 uint4 B-loads, blows the
// 128-unified-reg budget (64 arch + 64 acc) and spills to scratch (R9: 94 us).
__global__ __launch_bounds__(1024, 4) void kan_mfma(const float* __restrict__ x,
                                                    const unsigned short* __restrict__ cfb3,
                                                    float* __restrict__ out) {
    __shared__ float sxT[128][33];              // x transposed: read sxT[i][r] conflict-free
    __shared__ __align__(16) float red[32][128];
    __shared__ float xsr[32];

    const int t = threadIdx.x;
    const int w = t >> 6;          // wave = K-slice 0..15
    const int l = t & 63;
    const int r = l & 31;          // batch row within tile / B o-lane
    const int h = l >> 5;          // k-octet half
    const int b0 = blockIdx.x << 5;

    // ---- stage x (transposed) + zero reduction buffers ----
    {
        float4 xv = ((const float4*)(x + (size_t)b0 * IN))[t];
        int row = t >> 5, c0 = (t & 31) << 2;
        sxT[c0 + 0][row] = xv.x;
        sxT[c0 + 1][row] = xv.y;
        sxT[c0 + 2][row] = xv.z;
        sxT[c0 + 3][row] = xv.w;
        ((float4*)&red[0][0])[t] = make_float4(0.f, 0.f, 0.f, 0.f);
        if (t < 32) xsr[t] = 0.f;
    }
    __syncthreads();

    f32x16 a0, a1, a2, a3;
    #pragma unroll
    for (int e = 0; e < 16; ++e) { a0[e] = 0.f; a1[e] = 0.f; a2[e] = 0.f; a3[e] = 0.f; }
    float xs = 0.f;
    const uint4* bbase = (const uint4*)cfb3;

    // ---- 8 main steps: one 16-wide cell per MFMA, A-frag built in-lane ----
    #pragma unroll 1
    for (int s = 0; s < 8; ++s) {
        const int i = (w << 3) + s;
        const uint4* bq = bbase + (((i << 1) + h) << 7);
        uint4 B0 = bq[r], B1 = bq[r + 32], B2 = bq[r + 64], B3 = bq[r + 96];

        float xt = fast_tanh(sxT[i][r]);
        xs += (h == 0) ? xt : 0.f;
        float sc = (xt + 1.0f) * 7.5f;          // (xt+1)/grid_h, grid_h = 2/15
        int m = (int)sc; m = m < 0 ? 0 : (m > 14 ? 14 : m);
        float u = sc - (float)m, om = 1.f - u, u2 = u * u;
        float w0 = (1.f / 6.f) * om * om * om;
        float w1 = (2.f / 3.f) - u2 * (1.f - 0.5f * u);
        float w2 = (1.f / 6.f) + 0.5f * (u + u2 - u2 * u);
        float w3 = (1.f / 6.f) * u * u2;
        unsigned lo = (unsigned)f2bf(w0) | ((unsigned)f2bf(w1) << 16);
        unsigned hi = (unsigned)f2bf(w2) | ((unsigned)f2bf(w3) << 16);
        int odd = m & 1, dq = m >> 1;
        unsigned t0 = odd ? (lo << 16) : lo;
        unsigned t1 = odd ? ((hi << 16) | (lo >> 16)) : hi;
        unsigned t2 = odd ? (hi >> 16) : 0u;
        // lane's 4 dwords d = 4h+j of the 8-dword cell; taps at dq..dq+2
        // (dq+2 may be 8 -> cols 16/17 -> handled by the spill segment)
        uint4 af;
        {
            int d0 = h << 2;
            af.x = (d0 + 0 == dq) ? t0 : (d0 + 0 == dq + 1) ? t1 : (d0 + 0 == dq + 2) ? t2 : 0u;
            af.y = (d0 + 1 == dq) ? t0 : (d0 + 1 == dq + 1) ? t1 : (d0 + 1 == dq + 2) ? t2 : 0u;
            af.z = (d0 + 2 == dq) ? t0 : (d0 + 2 == dq + 1) ? t1 : (d0 + 2 == dq + 2) ? t2 : 0u;
            af.w = (d0 + 3 == dq) ? t0 : (d0 + 3 == dq + 1) ? t1 : (d0 + 3 == dq + 2) ? t2 : 0u;
        }
        a0 = __builtin_amdgcn_mfma_f32_32x32x16_bf16(as_bf16x8(af), as_bf16x8(B0), a0, 0, 0, 0);
        a1 = __builtin_amdgcn_mfma_f32_32x32x16_bf16(as_bf16x8(af), as_bf16x8(B1), a1, 0, 0, 0);
        a2 = __builtin_amdgcn_mfma_f32_32x32x16_bf16(as_bf16x8(af), as_bf16x8(B2), a2, 0, 0, 0);
        a3 = __builtin_amdgcn_mfma_f32_32x32x16_bf16(as_bf16x8(af), as_bf16x8(B3), a3, 0, 0, 0);
    }

    // ---- spill step ss=w: cols 16/17 of 8 cells (nonzero only when m>=13) ----
    {
        const int ss = w;
        const uint4* bq = bbase + ((256 + (ss << 1) + h) << 7);
        uint4 B0 = bq[r], B1 = bq[r + 32], B2 = bq[r + 64], B3 = bq[r + 96];
        unsigned ad[4];
        #pragma unroll
        for (int j = 0; j < 4; ++j) {
            int i = (ss << 3) + (h << 2) + j;
            float xt = fast_tanh(sxT[i][r]);
            float sc = (xt + 1.0f) * 7.5f;
            int m = (int)sc; m = m < 0 ? 0 : (m > 14 ? 14 : m);
            float u = sc - (float)m, u2 = u * u;
            float w2 = (1.f / 6.f) + 0.5f * (u + u2 - u2 * u);
            float w3 = (1.f / 6.f) * u * u2;
            ad[j] = (m == 14) ? ((unsigned)f2bf(w2) | ((unsigned)f2bf(w3) << 16))
                  : (m == 13) ? (unsigned)f2bf(w3) : 0u;
        }
        uint4 af; af.x = ad[0]; af.y = ad[1]; af.z = ad[2]; af.w = ad[3];
        a0 = __builtin_amdgcn_mfma_f32_32x32x16_bf16(as_bf16x8(af), as_bf16x8(B0), a0, 0, 0, 0);
        a1 = __builtin_amdgcn_mfma_f32_32x32x16_bf16(as_bf16x8(af), as_bf16x8(B1), a1, 0, 0, 0);
        a2 = __builtin_amdgcn_mfma_f32_32x32x16_bf16(as_bf16x8(af), as_bf16x8(B2), a2, 0, 0, 0);
        a3 = __builtin_amdgcn_mfma_f32_32x32x16_bf16(as_bf16x8(af), as_bf16x8(B3), a3, 0, 0, 0);
    }

    // ---- K-reduction: LDS fp32 atomics (no inter-wave ordering needed) ----
    if (h == 0) atomicAdd(&xsr[r], xs);
    #pragma unroll
    for (int e = 0; e < 16; ++e) {
        int row = (e & 3) + ((e >> 2) << 3) + (h << 2);   // C/D row mapping
        atomicAdd(&red[row][r],      a0[e]);
        atomicAdd(&red[row][r + 32], a1[e]);
        atomicAdd(&red[row][r + 64], a2[e]);
        atomicAdd(&red[row][r + 96], a3[e]);
    }
    __syncthreads();

    // ---- epilogue: coalesced float4 store ----
    {
        float4 v = ((const float4*)&red[0][0])[t];
        float xm = xsr[t >> 5];
        float4 o4;
        o4.x = (v.x + xm) * (1.0f / 128.0f);
        o4.y = (v.y + xm) * (1.0f / 128.0f);
        o4.z = (v.z + xm) * (1.0f / 128.0f);
        o4.w = (v.w + xm) * (1.0f / 128.0f);
        ((float4*)(out + (size_t)b0 * OUT))[t] = o4;
    }
}

// ---------------- fallback (ws too small): R3's proven VALU kernel ----------------
__global__ __launch_bounds__(256, 2) void kan_valu(const float* __restrict__ x,
                                                   const float* __restrict__ cf,
                                                   float* __restrict__ out) {
    __shared__ float4        s_w[16][IN];
    __shared__ unsigned char s_m[16][IN];
    __shared__ float         s_xs[16];
    const int t = threadIdx.x;
    const int boff = blockIdx.x * 16;
    {
        const int b = t >> 4, il = t & 15;
        float xs = 0.f;
        #pragma unroll
        for (int k = 0; k < IN / 16; ++k) {
            int i = il + 16 * k;
            float xt = tanhf(x[(boff + b) * IN + i]);
            xs += xt;
            float s = (xt + 1.0f) * 7.5f;
            int m = (int)s; m = m < 0 ? 0 : (m > 14 ? 14 : m);
            float u = s - (float)m, om = 1.f - u, u2 = u * u;
            s_w[b][i] = make_float4((1.f/6.f)*om*om*om,
                                    (2.f/3.f) - u2*(1.f - 0.5f*u),
                                    (1.f/6.f) + 0.5f*(u + u2 - u2*u),
                                    (1.f/6.f)*u*u2);
            s_m[b][i] = (unsigned char)m;
        }
        for (int d = 8; d > 0; d >>= 1) xs += __shfl_down(xs, d, 16);
        if (il == 0) s_xs[b] = xs;
    }
    __syncthreads();
    const int w = t >> 6, l = t & 63;
    #pragma unroll
    for (int r = 0; r < 4; ++r) {
        const int b = w * 4 + r;
        float a0 = 0.f, a1 = 0.f;
        for (int i = 0; i < IN; ++i) {
            float4 wv = s_w[b][i];
            int m = (int)s_m[b][i];
            const float* p0 = cf + (2 * l) * ROW + i * 18 + m;
            const float* p1 = p0 + ROW;
            a0 += wv.x * p0[0] + wv.y * p0[1] + wv.z * p0[2] + wv.w * p0[3];
            a1 += wv.x * p1[0] + wv.y * p1[1] + wv.z * p1[2] + wv.w * p1[3];
        }
        float xsv = s_xs[b];
        float2 st; st.x = (xsv + a0) / 128.f; st.y = (xsv + a1) / 128.f;
        ((float2*)out)[(boff + b) * (OUT / 2) + l] = st;
    }
}

extern "C" void kernel_launch(void* const* d_in, const int* in_sizes, int n_in,
                              void* d_out, int out_size, void* d_ws, size_t ws_size,
                              hipStream_t stream) {
    const float* x  = (const float*)d_in[0];
    const float* cf = (const float*)d_in[1];
    float* out = (float*)d_out;
    if (ws_size >= (size_t)WS_NEED) {
        unsigned short* cfb3 = (unsigned short*)d_ws;
        cvt_kernel<<<144, 256, 0, stream>>>(cf, cfb3);
        kan_mfma<<<BATCH / 32, 1024, 0, stream>>>(x, cfb3, out);
    } else {
        kan_valu<<<BATCH / 16, 256, 0, stream>>>(x, cf, out);
    }
}

// Round 11
// 81.613 us; speedup vs baseline: 1.8280x; 1.8280x over previous
//
#include <hip/hip_runtime.h>

#define BATCH 8192
#define IN 128
#define OUT 128
#define ROW (IN * 18)            // 2304 floats per cf output row
#define WS_NEED (294912u * 2u)   // 576 KB bf16 re-tiled cf
#define PANEL_DW (288 * 128)     // 147456 B LDS A-panel: [octet q][row*4+dw]

typedef short bf16x8 __attribute__((ext_vector_type(8)));
typedef float f32x16 __attribute__((ext_vector_type(16)));

static __device__ __forceinline__ unsigned short f2bf(float f) {
    union { float f; unsigned u; } v; v.f = f;
    unsigned r = v.u + 0x7fffu + ((v.u >> 16) & 1u);   // RNE
    return (unsigned short)(r >> 16);
}
static __device__ __forceinline__ bf16x8 as_bf16x8(uint4 v) {
    union { uint4 u; bf16x8 b; } x; x.u = v; return x.b;
}
static __device__ __forceinline__ float fast_tanh(float v) {
    float e = __expf(2.0f * v);
    return 1.0f - 2.0f * __builtin_amdgcn_rcpf(e + 1.0f);
}

// cf fp32 [o][k] -> cfb3 bf16 octet-major [q][o][8], q = 0..287:
// main q = 2i + c8 -> cf[o][18i + 8*c8 + e]; spill q = 256+qs -> cols 16/17.
// (byte-identical to R9/R10 — numerics proven)
__global__ __launch_bounds__(256) void cvt_kernel(const float* __restrict__ cf,
                                                  unsigned short* __restrict__ cfb3) {
    int tid = blockIdx.x * 256 + threadIdx.x;   // 0 .. 36863
    int o = tid & 127;
    int q = tid >> 7;                           // 0..287
    unsigned short v[8];
    if (q < 256) {
        const float* p = cf + o * ROW + (q >> 1) * 18 + (q & 1) * 8;
        #pragma unroll
        for (int e = 0; e < 8; ++e) v[e] = f2bf(p[e]);
    } else {
        int qs = q - 256;
        #pragma unroll
        for (int e = 0; e < 8; ++e) {
            int kl = qs * 8 + e;
            v[e] = f2bf(cf[o * ROW + (kl >> 1) * 18 + 16 + (kl & 1)]);
        }
    }
    uint4 pk;
    pk.x = (unsigned)v[0] | ((unsigned)v[1] << 16);
    pk.y = (unsigned)v[2] | ((unsigned)v[3] << 16);
    pk.z = (unsigned)v[4] | ((unsigned)v[5] << 16);
    pk.w = (unsigned)v[6] | ((unsigned)v[7] << 16);
    ((uint4*)cfb3)[q * 128 + o] = pk;
}

// 256 blocks x 256 thr (4 waves), 1 block/CU (144KB LDS).
// Phase 1: build the ENTIRE 32-row A-panel (K=2304 incl. spill) in LDS once.
// Phase 2: each wave streams its 32-o N-slice through 144 uniform K16 steps —
// ds_read_b128 A + rolling-8 B prefetch + MFMA, zero barriers, no K-split.
__global__ __launch_bounds__(256, 1) void kan_mfma(const float* __restrict__ x,
                                                   const unsigned short* __restrict__ cfb3,
                                                   float* __restrict__ out) {
    __shared__ unsigned sP[PANEL_DW];   // 144 KB A-panel
    __shared__ float xsr[32];

    const int t  = threadIdx.x;
    const int b0 = blockIdx.x << 5;

    if (t < 32) xsr[t] = 0.f;
    __syncthreads();

    // ---- Phase 1: build 16 cells per thread (row ab, i = seg*16 + s2) ----
    {
        const int ab = t & 31;
        const int seg = t >> 5;     // all 16 x-reads of a seg hit ONE 64B line
        float xs = 0.f;
        for (int s2 = 0; s2 < 16; ++s2) {
            int i = (seg << 4) + s2;
            float xt = fast_tanh(x[(b0 + ab) * IN + i]);
            xs += xt;
            float sc = (xt + 1.0f) * 7.5f;      // (xt+1)/h, h = 2/15
            int m = (int)sc; m = m < 0 ? 0 : (m > 14 ? 14 : m);
            float u = sc - (float)m, om = 1.f - u, u2 = u * u;
            float w0 = (1.f / 6.f) * om * om * om;
            float w1 = (2.f / 3.f) - u2 * (1.f - 0.5f * u);
            float w2 = (1.f / 6.f) + 0.5f * (u + u2 - u2 * u);
            float w3 = (1.f / 6.f) * u * u2;
            unsigned lo = (unsigned)f2bf(w0) | ((unsigned)f2bf(w1) << 16);
            unsigned hi = (unsigned)f2bf(w2) | ((unsigned)f2bf(w3) << 16);
            int odd = m & 1, dq = m >> 1;
            unsigned t0 = odd ? (lo << 16) : lo;
            unsigned t1 = odd ? ((hi << 16) | (lo >> 16)) : hi;
            unsigned t2 = odd ? (hi >> 16) : 0u;
            unsigned cell[9];                   // dword d = cols (2d, 2d+1) of 18
            #pragma unroll
            for (int jj = 0; jj < 9; ++jj)      // m=14: t2 would sit at d9 but ==0
                cell[jj] = (jj == dq) ? t0 : (jj == dq + 1) ? t1
                         : (jj == dq + 2) ? t2 : 0u;
            unsigned* p0 = sP + ((i << 1) << 7) + (ab << 2);
            *(uint4*)p0         = make_uint4(cell[0], cell[1], cell[2], cell[3]);
            *(uint4*)(p0 + 128) = make_uint4(cell[4], cell[5], cell[6], cell[7]);
            sP[((256 + (i >> 2)) << 7) + (ab << 2) + (i & 3)] = cell[8];  // spill
        }
        atomicAdd(&xsr[ab], xs);
    }
    __syncthreads();    // the ONLY work barrier

    // ---- Phase 2: 144-step uniform stream (octets 2s, 2s+1) ----
    const int w  = t >> 6;
    const int l  = t & 63;
    const int am = l & 31;          // A row / C col
    const int h  = l >> 5;          // k-octet half
    const int n0 = w << 5;          // N-slice

    const uint4* bb = (const uint4*)cfb3 + (h << 7) + n0 + am;  // +256/step
    const unsigned* ap = sP + (h << 7) + (am << 2);             // +256 dw/step

    f32x16 acc;
    #pragma unroll
    for (int e = 0; e < 16; ++e) acc[e] = 0.f;

    uint4 Bq[8];
    #pragma unroll
    for (int p = 0; p < 8; ++p) Bq[p] = bb[p << 8];

    #pragma unroll 8
    for (int s = 0; s < 144; ++s) {
        uint4 bv = Bq[s & 7];
        if (s + 8 < 144) Bq[s & 7] = bb[(s + 8) << 8];
        uint4 av = *(const uint4*)(ap + (s << 8));
        acc = __builtin_amdgcn_mfma_f32_32x32x16_bf16(
                  as_bf16x8(av), as_bf16x8(bv), acc, 0, 0, 0);
    }

    // ---- epilogue: C/D col=l&31, row=(r&3)+8*(r>>2)+4*h (proven mapping) ----
    #pragma unroll
    for (int r = 0; r < 16; ++r) {
        int row = (r & 3) + ((r >> 2) << 3) + (h << 2);
        out[(b0 + row) * OUT + n0 + am] = (acc[r] + xsr[row]) * (1.0f / 128.0f);
    }
}

// ---------------- fallback (ws too small): R3's proven VALU kernel ----------------
__global__ __launch_bounds__(256, 2) void kan_valu(const float* __restrict__ x,
                                                   const float* __restrict__ cf,
                                                   float* __restrict__ out) {
    __shared__ float4        s_w[16][IN];
    __shared__ unsigned char s_m[16][IN];
    __shared__ float         s_xs[16];
    const int t = threadIdx.x;
    const int boff = blockIdx.x * 16;
    {
        const int b = t >> 4, il = t & 15;
        float xs = 0.f;
        #pragma unroll
        for (int k = 0; k < IN / 16; ++k) {
            int i = il + 16 * k;
            float xt = tanhf(x[(boff + b) * IN + i]);
            xs += xt;
            float s = (xt + 1.0f) * 7.5f;
            int m = (int)s; m = m < 0 ? 0 : (m > 14 ? 14 : m);
            float u = s - (float)m, om = 1.f - u, u2 = u * u;
            s_w[b][i] = make_float4((1.f/6.f)*om*om*om,
                                    (2.f/3.f) - u2*(1.f - 0.5f*u),
                                    (1.f/6.f) + 0.5f*(u + u2 - u2*u),
                                    (1.f/6.f)*u*u2);
            s_m[b][i] = (unsigned char)m;
        }
        for (int d = 8; d > 0; d >>= 1) xs += __shfl_down(xs, d, 16);
        if (il == 0) s_xs[b] = xs;
    }
    __syncthreads();
    const int w = t >> 6, l = t & 63;
    #pragma unroll
    for (int r = 0; r < 4; ++r) {
        const int b = w * 4 + r;
        float a0 = 0.f, a1 = 0.f;
        for (int i = 0; i < IN; ++i) {
            float4 wv = s_w[b][i];
            int m = (int)s_m[b][i];
            const float* p0 = cf + (2 * l) * ROW + i * 18 + m;
            const float* p1 = p0 + ROW;
            a0 += wv.x * p0[0] + wv.y * p0[1] + wv.z * p0[2] + wv.w * p0[3];
            a1 += wv.x * p1[0] + wv.y * p1[1] + wv.z * p1[2] + wv.w * p1[3];
        }
        float xsv = s_xs[b];
        float2 st; st.x = (xsv + a0) / 128.f; st.y = (xsv + a1) / 128.f;
        ((float2*)out)[(boff + b) * (OUT / 2) + l] = st;
    }
}

extern "C" void kernel_launch(void* const* d_in, const int* in_sizes, int n_in,
                              void* d_out, int out_size, void* d_ws, size_t ws_size,
                              hipStream_t stream) {
    const float* x  = (const float*)d_in[0];
    const float* cf = (const float*)d_in[1];
    float* out = (float*)d_out;
    if (ws_size >= (size_t)WS_NEED) {
        unsigned short* cfb3 = (unsigned short*)d_ws;
        cvt_kernel<<<144, 256, 0, stream>>>(cf, cfb3);
        kan_mfma<<<BATCH / 32, 256, 0, stream>>>(x, cfb3, out);
    } else {
        kan_valu<<<BATCH / 16, 256, 0, stream>>>(x, cf, out);
    }
}